// Round 1
// baseline (357.196 us; speedup 1.0000x reference)
//
#include <hip/hip_runtime.h>

#define B_ 8
#define L_ 4800
#define H_ 8
#define D_ 64
#define BH_ 64

// Workspace layout (float offsets)
#define G_ELEMS (BH_*D_*D_)          // 262144
#define QSQ_OFF G_ELEMS              // 262144
#define KSQ_OFF (QSQ_OFF + BH_*D_)   // 266240
#define M_OFF   (KSQ_OFF + BH_*D_)   // 270336

#define NCH 12
#define CHUNK (L_/NCH)               // 400, multiple of 8

// ---------------------------------------------------------------------------
// Kernel A: per (b,h) Gram matrix G = q^T k over L (chunked), plus sum-of-
// squares of q and k rows.  atomicAdd partials into zeroed workspace.
// ---------------------------------------------------------------------------
__global__ __launch_bounds__(256) void gram_kernel(
    const float* __restrict__ q, const float* __restrict__ k,
    float* __restrict__ G, float* __restrict__ qsq, float* __restrict__ ksq)
{
  const int bh = blockIdx.y;
  const int b = bh >> 3, h = bh & 7;
  const int l0 = blockIdx.x * CHUNK;
  const int t = threadIdx.x;
  const int tx = t & 15, ty = t >> 4;   // 16x16 thread tile -> 4x4 G elements each

  __shared__ float Lq[8][64];
  __shared__ float Lk[8][64];

  // staging: threads 0..127 load q rows, 128..255 load k rows (8 rows x 16 float4)
  const int sr = (t & 127) >> 4;        // 0..7 (l offset within 8-row slab)
  const int sc = (t & 15) * 4;          // 0..60 (d offset)
  const bool isQ = (t < 128);
  const float* __restrict__ src = isQ ? q : k;
  const float* sp = src + (((size_t)(b*L_ + l0 + sr))*H_ + h)*D_ + sc;

  float sq0=0.f, sq1=0.f, sq2=0.f, sq3=0.f;
  float acc[4][4] = {};

  for (int ls = 0; ls < CHUNK; ls += 8) {
    float4 v4 = *(const float4*)sp;
    sp += 8*H_*D_;
    __syncthreads();                    // previous slab fully consumed
    *(float4*)(isQ ? &Lq[sr][sc] : &Lk[sr][sc]) = v4;
    sq0 += v4.x*v4.x; sq1 += v4.y*v4.y; sq2 += v4.z*v4.z; sq3 += v4.w*v4.w;
    __syncthreads();
#pragma unroll
    for (int r = 0; r < 8; r++) {
      float4 qa4 = *(const float4*)&Lq[r][ty*4];
      float4 kb4 = *(const float4*)&Lk[r][tx*4];
      float qa[4] = {qa4.x,qa4.y,qa4.z,qa4.w};
      float kb[4] = {kb4.x,kb4.y,kb4.z,kb4.w};
#pragma unroll
      for (int i = 0; i < 4; i++)
#pragma unroll
        for (int j = 0; j < 4; j++)
          acc[i][j] = fmaf(qa[i], kb[j], acc[i][j]);
    }
  }

  float* nacc = isQ ? qsq : ksq;
  atomicAdd(&nacc[bh*64 + sc + 0], sq0);
  atomicAdd(&nacc[bh*64 + sc + 1], sq1);
  atomicAdd(&nacc[bh*64 + sc + 2], sq2);
  atomicAdd(&nacc[bh*64 + sc + 3], sq3);

  float* g = G + (size_t)bh*4096;
#pragma unroll
  for (int i = 0; i < 4; i++)
#pragma unroll
    for (int j = 0; j < 4; j++)
      atomicAdd(&g[(ty*4+i)*64 + tx*4 + j], acc[i][j]);
}

// ---------------------------------------------------------------------------
// Kernel B: per (b,h) 64x64 postprocessing: normalize, gates, temperature,
// 4x exact top-k (rank counting, tie-exact) + masked softmax, combine into M.
// One block per (b,h), 256 threads: thread = (d = t&63, quarter q4 = t>>6).
// ---------------------------------------------------------------------------
__global__ __launch_bounds__(256) void mask_kernel(
    const float* __restrict__ G, const float* __restrict__ qsq,
    const float* __restrict__ ksq,
    const float* __restrict__ temperature, const float* __restrict__ attns,
    const float* __restrict__ row_w, const float* __restrict__ row_b,
    const float* __restrict__ col_w, const float* __restrict__ col_b,
    float* __restrict__ M)
{
  const int bh = blockIdx.x;
  const int h = bh & 7;
  const int t = threadIdx.x;
  const int d = t & 63, q4 = t >> 6;
  const int e0 = q4 * 16;

  __shared__ float att[64][65];
  __shared__ float rnq[64], rnk[64], cw[64], rw[64];
  __shared__ float wcol[64], wrow[64];
  __shared__ float thr[4][64];
  __shared__ float pmax[4][64];
  __shared__ float rowmax[64];
  __shared__ float psum[4][4][64];   // [q4][tk][d]
  __shared__ float rinv[4][64];

  if (t < 64)        rnq[t]     = 1.0f / fmaxf(sqrtf(qsq[bh*64 + t]), 1e-12f);
  else if (t < 128)  rnk[t-64]  = 1.0f / fmaxf(sqrtf(ksq[bh*64 + t-64]), 1e-12f);
  else if (t < 192)  cw[t-128]  = col_w[t-128];
  else               rw[t-192]  = row_w[t-192];
  __syncthreads();

  {
    const float* gp = G + (size_t)bh*4096 + d*64 + e0;
    float rq = rnq[d];
#pragma unroll
    for (int ee = 0; ee < 16; ee++)
      att[d][e0+ee] = gp[ee] * rq * rnk[e0+ee];
  }
  __syncthreads();

  if (t < 64) {                       // w_col[e], e = t
    float s = 0.f;
    for (int c = 0; c < 64; c++) s += att[c][t] * cw[c];
    s += col_b[0];
    wcol[t] = 1.0f / (1.0f + __expf(-s));
  } else if (t < 128) {               // w_row[c], c = t-64
    int c = t - 64;
    float s = 0.f;
    for (int e = 0; e < 64; e++) s += att[c][e] * rw[e];
    s += row_b[0];
    wrow[c] = 1.0f / (1.0f + __expf(-s));
  }
  __syncthreads();

  {
    const float temp = temperature[h];
    const float wr = wrow[d];
    float mx = -1e30f;
#pragma unroll
    for (int ee = 0; ee < 16; ee++) {
      float x = att[d][e0+ee] * ((wcol[e0+ee] + wr) * temp);
      att[d][e0+ee] = x;
      mx = fmaxf(mx, x);
    }
    pmax[q4][d] = mx;
  }
  __syncthreads();
  if (t < 64)
    rowmax[t] = fmaxf(fmaxf(pmax[0][t], pmax[1][t]), fmaxf(pmax[2][t], pmax[3][t]));

  // exact k-th largest by rank counting (matches top_k incl. ties):
  // value x is the tk-th largest iff count(>x) <= tk-1 and count(>=x) >= tk.
  {
    float x[16];
#pragma unroll
    for (int j = 0; j < 16; j++) x[j] = att[d][e0+j];
    int gt[16] = {}, ge[16] = {};
    for (int m = 0; m < 64; m++) {
      float y = att[d][m];
#pragma unroll
      for (int j = 0; j < 16; j++) { gt[j] += (y > x[j]); ge[j] += (y >= x[j]); }
    }
    const int tks[4] = {32, 42, 48, 51};
#pragma unroll
    for (int j = 0; j < 16; j++)
#pragma unroll
      for (int i = 0; i < 4; i++)
        if (gt[j] <= tks[i]-1 && ge[j] >= tks[i]) thr[i][d] = x[j];
  }
  __syncthreads();

  {
    const float rm = rowmax[d];
    const float t0 = thr[0][d], t1 = thr[1][d], t2 = thr[2][d], t3 = thr[3][d];
    float s0=0.f, s1=0.f, s2=0.f, s3=0.f;
#pragma unroll
    for (int ee = 0; ee < 16; ee++) {
      float xv = att[d][e0+ee];
      float ex = __expf(xv - rm);
      if (xv >= t0) s0 += ex;
      if (xv >= t1) s1 += ex;
      if (xv >= t2) s2 += ex;
      if (xv >= t3) s3 += ex;
    }
    psum[q4][0][d] = s0; psum[q4][1][d] = s1; psum[q4][2][d] = s2; psum[q4][3][d] = s3;
  }
  __syncthreads();
  if (t < 64) {
#pragma unroll
    for (int i = 0; i < 4; i++) {
      float s = psum[0][i][t] + psum[1][i][t] + psum[2][i][t] + psum[3][i][t];
      rinv[i][t] = attns[i] / s;
    }
  }
  __syncthreads();

  {
    const float rm = rowmax[d];
    const float t0 = thr[0][d], t1 = thr[1][d], t2 = thr[2][d], t3 = thr[3][d];
    const float r0 = rinv[0][d], r1 = rinv[1][d], r2 = rinv[2][d], r3 = rinv[3][d];
    float* mo = M + (size_t)bh*4096 + d*64 + e0;
#pragma unroll
    for (int ee = 0; ee < 16; ee++) {
      float xv = att[d][e0+ee];
      float ex = __expf(xv - rm);
      float m = 0.f;
      if (xv >= t0) m += r0 * ex;
      if (xv >= t1) m += r1 * ex;
      if (xv >= t2) m += r2 * ex;
      if (xv >= t3) m += r3 * ex;
      mo[ee] = m;
    }
  }
}

// ---------------------------------------------------------------------------
// Kernel C: out[b,l,h,:] = M_bh * v[b,l,h,:].  Block = (b,h) x 64 l's.
// M staged transposed [e][d] (stride 68 -> 2-way bank alias = free),
// v staged [l][e].  4x4 register tile (d x l) per thread.
// ---------------------------------------------------------------------------
__global__ __launch_bounds__(256) void apply_kernel(
    const float* __restrict__ M, const float* __restrict__ v,
    float* __restrict__ out)
{
  const int bh = blockIdx.y;
  const int b = bh >> 3, h = bh & 7;
  const int l0 = blockIdx.x * 64;
  const int t = threadIdx.x;

  __shared__ float Ms[64][68];   // [e][d]
  __shared__ float Vs[64][68];   // [l][e]

#pragma unroll
  for (int i = 0; i < 4; i++) {
    int idx = t + i*256;                 // 0..1023 float4s
    int dd = idx >> 4;                   // 0..63
    int c4 = (idx & 15) * 4;             // 0..60
    float4 mv = *(const float4*)(M + (size_t)bh*4096 + dd*64 + c4);
    Ms[c4+0][dd] = mv.x; Ms[c4+1][dd] = mv.y; Ms[c4+2][dd] = mv.z; Ms[c4+3][dd] = mv.w;
    float4 vv = *(const float4*)(v + (((size_t)b*L_ + l0 + dd)*H_ + h)*D_ + c4);
    *(float4*)&Vs[dd][c4] = vv;
  }
  __syncthreads();

  const int dq = t & 15, lq = t >> 4;
  const int d0 = dq * 4, lr = lq * 4;
  float acc[4][4] = {};                  // [i=d][j=l]

#pragma unroll
  for (int e4 = 0; e4 < 16; e4++) {
    const int e = e4 * 4;
    float4 m0 = *(const float4*)&Ms[e+0][d0];
    float4 m1 = *(const float4*)&Ms[e+1][d0];
    float4 m2 = *(const float4*)&Ms[e+2][d0];
    float4 m3 = *(const float4*)&Ms[e+3][d0];
    float ma[4][4] = {{m0.x,m0.y,m0.z,m0.w},{m1.x,m1.y,m1.z,m1.w},
                      {m2.x,m2.y,m2.z,m2.w},{m3.x,m3.y,m3.z,m3.w}}; // [ee][i]
#pragma unroll
    for (int j = 0; j < 4; j++) {
      float4 vj = *(const float4*)&Vs[lr+j][e];
      float va[4] = {vj.x, vj.y, vj.z, vj.w};                        // [ee]
#pragma unroll
      for (int i = 0; i < 4; i++) {
        acc[i][j] = fmaf(ma[0][i], va[0], acc[i][j]);
        acc[i][j] = fmaf(ma[1][i], va[1], acc[i][j]);
        acc[i][j] = fmaf(ma[2][i], va[2], acc[i][j]);
        acc[i][j] = fmaf(ma[3][i], va[3], acc[i][j]);
      }
    }
  }

#pragma unroll
  for (int j = 0; j < 4; j++) {
    int l = l0 + lr + j;
    float4 o = make_float4(acc[0][j], acc[1][j], acc[2][j], acc[3][j]);
    *(float4*)(out + (((size_t)b*L_ + l)*H_ + h)*D_ + d0) = o;
  }
}

// ---------------------------------------------------------------------------
extern "C" void kernel_launch(void* const* d_in, const int* in_sizes, int n_in,
                              void* d_out, int out_size, void* d_ws, size_t ws_size,
                              hipStream_t stream) {
  const float* q           = (const float*)d_in[0];
  const float* k           = (const float*)d_in[1];
  const float* v           = (const float*)d_in[2];
  const float* temperature = (const float*)d_in[3];
  const float* attns       = (const float*)d_in[4];
  const float* row_w       = (const float*)d_in[5];
  const float* row_b       = (const float*)d_in[6];
  const float* col_w       = (const float*)d_in[7];
  const float* col_b       = (const float*)d_in[8];
  float* out = (float*)d_out;

  float* ws  = (float*)d_ws;
  float* G   = ws;
  float* qsq = ws + QSQ_OFF;
  float* ksq = ws + KSQ_OFF;
  float* M   = ws + M_OFF;

  // zero the atomic accumulators (G, qsq, ksq); M is fully overwritten
  hipMemsetAsync(ws, 0, (size_t)M_OFF * sizeof(float), stream);

  gram_kernel<<<dim3(NCH, BH_), 256, 0, stream>>>(q, k, G, qsq, ksq);
  mask_kernel<<<dim3(BH_), 256, 0, stream>>>(G, qsq, ksq, temperature, attns,
                                             row_w, row_b, col_w, col_b, M);
  apply_kernel<<<dim3(L_/64, BH_), 256, 0, stream>>>(M, v, out);
}